// Round 10
// baseline (160.250 us; speedup 1.0000x reference)
//
#include <hip/hip_runtime.h>
#include <hip/hip_bf16.h>
#include <stdint.h>

#define TOK   256
#define NOBJ  64
#define NDEMO 16
#define BATCH 256
#define SEQ   1105              /* 1 + 16*65 + 64 */
#define NDG   (NDEMO * BATCH)   /* 4096 demo groups */
#define NGRP  (NDG + BATCH)     /* 4352 total groups */
#define NQT   (NGRP * 4)        /* 17408 quarter-tiles (16 rows each) */
#define OBJ_BLKS   512
#define NG    (NQT / OBJ_BLKS)  /* 34 quarter-tiles per block */
#define ACT_BLKS   512
#define INSTR_BLKS 128
#define TOTAL_BLKS (OBJ_BLKS + ACT_BLKS + INSTR_BLKS)

typedef __bf16 bf16x8 __attribute__((ext_vector_type(8)));
typedef float  f32x4  __attribute__((ext_vector_type(4)));

static __device__ __forceinline__ unsigned pack_bf16x2(float a, float b) {
    unsigned ua = __float_as_uint(a);
    unsigned ub = __float_as_uint(b);
    unsigned ra = (ua + 0x7FFFu + ((ua >> 16) & 1u)) >> 16;
    unsigned rb = (ub + 0x7FFFu + ((ub >> 16) & 1u)) >> 16;
    return (ra & 0xFFFFu) | (rb << 16);
}

static __device__ __forceinline__ bf16x8 pack8n(float4 lo, float4 hi) {
    bf16x8 o;
    o[0] = (__bf16)lo.x; o[1] = (__bf16)lo.y;
    o[2] = (__bf16)lo.z; o[3] = (__bf16)lo.w;
    o[4] = (__bf16)hi.x; o[5] = (__bf16)hi.y;
    o[6] = (__bf16)hi.z; o[7] = (__bf16)hi.w;
    return o;
}

// direct global->LDS, 16B per lane (dest linear: wave-uniform base + lane*16)
static __device__ __forceinline__ void gload_lds16(const float* g, void* l) {
    __builtin_amdgcn_global_load_lds(
        (const __attribute__((address_space(1))) uint32_t*)g,
        (__attribute__((address_space(3))) uint32_t*)l,
        16, 0, 0);
}

// ---------------------------------------------------------------------------
// Prologue: W_obj (f32 [k=256][t=256]) -> Wf, bf16 in MFMA fragment order:
// chunk q = ((wc*4 + j)*8 + s)*64 + lane  holds W[k = s*32+(lane>>4)*8 .. +7]
// [t = wc*64+j*16+(lane&15)] -- the A-operand (W^T) fragment stream.
// ---------------------------------------------------------------------------
__global__ void wconv_frag_kernel(const float* __restrict__ W, uint16_t* __restrict__ Wf) {
    int q = blockIdx.x * 256 + threadIdx.x;   // 8192 chunks of 16B
    int lane = q & 63;
    int s  = (q >> 6) & 7;
    int j  = (q >> 9) & 3;
    int wc = (q >> 11) & 3;
    int tcol = wc * 64 + j * 16 + (lane & 15);
    int k0   = s * 32 + (lane >> 4) * 8;
    uint4 w;
    unsigned p[4];
#pragma unroll
    for (int h = 0; h < 4; ++h) {
        float a = W[(size_t)(k0 + 2 * h)     * TOK + tcol];
        float b = W[(size_t)(k0 + 2 * h + 1) * TOK + tcol];
        p[h] = pack_bf16x2(a, b);
    }
    w.x = p[0]; w.y = p[1]; w.z = p[2]; w.w = p[3];
    *reinterpret_cast<uint4*>(Wf + (size_t)q * 8) = w;
}

// ---------------------------------------------------------------------------
// Fused kernel, 512 threads/block. Grid roles:
//   [0, 512)         : obj GEMM — NG=34 16-row quarter-tiles per block,
//                      8 waves x 32 output cols, double-buffered 16KB DMA
//                      tiles, ONE barrier + per-wave vmcnt(2) per iteration.
//   [512, 1024)      : action rows (8 per block, 2x256-thread halves)
//   [1024, 1152)     : instr rows (2 per block, one per 256-thread half)
// ---------------------------------------------------------------------------
__global__ __launch_bounds__(512, 4) void fused_kernel(
    const float* __restrict__ demo_obj,   // (16,256,64,256)
    const float* __restrict__ cur,        // (256,64,256)
    const float* __restrict__ b_obj,      // (256,)
    const __bf16* __restrict__ Wf,        // fragment-ordered bf16 weights
    const float* __restrict__ demo_act,   // (16,256,7)
    const float* __restrict__ W_act,      // (7,256)
    const float* __restrict__ b_act,      // (256,)
    const float* __restrict__ instr,      // (256,768)
    const float* __restrict__ W_instr,    // (768,256)
    const float* __restrict__ b_instr,    // (256,)
    float* __restrict__ out)              // (256,1105,256)
{
    __shared__ __align__(16) float F[2][16 * TOK];   // 32 KB: two 16-row f32 tiles
    int blk = blockIdx.x;
    int tid = threadIdx.x;

    if (blk < OBJ_BLKS) {
        // ================= obj GEMM =================
        int h0 = blk * NG;
        int wave = tid >> 6, lane = tid & 63;
        int l15 = lane & 15, l4 = lane >> 4;
        int n0 = wave * 32;          // this wave's 32 output token cols
        int wc = wave >> 1;          // 64-col quarter in Wf order
        int jb = (wave & 1) * 2;     // j base within quarter

        // ---- W preload: 16 contiguous 1KB wave-loads -> 64 VGPR ----
        bf16x8 wf[2][8];
        {
            const __bf16* fb = Wf + (((size_t)(wc * 4 + jb) * 8) * 64 + lane) * 8;
#pragma unroll
            for (int jj = 0; jj < 2; ++jj)
#pragma unroll
                for (int s = 0; s < 8; ++s)
                    wf[jj][s] = *reinterpret_cast<const bf16x8*>(fb + (size_t)(jj * 8 + s) * 64 * 8);
        }
#pragma unroll
        for (int jj = 0; jj < 2; ++jj)
#pragma unroll
            for (int s = 0; s < 8; ++s)
                asm volatile("" : "+v"(wf[jj][s]));   // force wait into prologue

        f32x4 bv4[2];
#pragma unroll
        for (int jj = 0; jj < 2; ++jj) {
            bv4[jj] = *reinterpret_cast<const f32x4*>(b_obj + n0 + jj * 16 + l4 * 4);
            asm volatile("" : "+v"(bv4[jj]));
        }

        auto SRC = [&](int h) -> const float* {
            return (h < 4 * NDG) ? demo_obj + (size_t)h * (16 * TOK)
                                 : cur + (size_t)(h - 4 * NDG) * (16 * TOK);
        };
        auto STAGE = [&](int it) {
            const float* sb = SRC(h0 + it);
            float* dst = &F[it & 1][0];
#pragma unroll
            for (int i = 0; i < 2; ++i) {
                int slot = i * 512 + tid;           // 1024 chunks of 16B
                int r = slot >> 6, c = slot & 63;
                gload_lds16(sb + (size_t)(r * 64 + (c ^ (r & 7))) * 4,
                            dst + (size_t)slot * 4);
            }
        };

        STAGE(0);   // first tile's DMA in flight (2 loads/thread)

#pragma unroll 1
        for (int it = 0; it < NG; ++it) {
            // per-wave FIFO here: it==0 -> L_0(2); it>=1 -> L_it(2,oldest)+S_{it-1}(2)
            if (it == 0) asm volatile("s_waitcnt vmcnt(0)" ::: "memory");
            else         asm volatile("s_waitcnt vmcnt(2)" ::: "memory");
            __builtin_amdgcn_s_barrier();
            __builtin_amdgcn_sched_barrier(0);

            // DMA next tile into the other buffer (overlaps compute below)
            if (it + 1 < NG) STAGE(it + 1);

            const float* buf = &F[it & 1][0];

            f32x4 acc[2];
#pragma unroll
            for (int jj = 0; jj < 2; ++jj) {
                f32x4 z = {0.0f, 0.0f, 0.0f, 0.0f};
                acc[jj] = z;
            }

#pragma unroll
            for (int s = 0; s < 8; ++s) {
                int c0 = s * 8 + l4 * 2;
                float4 lo = *reinterpret_cast<const float4*>(
                    buf + l15 * TOK + (size_t)((c0 ^ (l15 & 7)) * 4));
                float4 hi = *reinterpret_cast<const float4*>(
                    buf + l15 * TOK + (size_t)(((c0 + 1) ^ (l15 & 7)) * 4));
                bf16x8 a = pack8n(lo, hi);
                acc[0] = __builtin_amdgcn_mfma_f32_16x16x32_bf16(wf[0][s], a, acc[0], 0, 0, 0);
                acc[1] = __builtin_amdgcn_mfma_f32_16x16x32_bf16(wf[1][s], a, acc[1], 0, 0, 0);
            }

            // ---- epilogue: 2 nontemporal float4 stores per thread ----
            int h = h0 + it;
            int g = h >> 2, q = h & 3;
            int row_base;
            if (h < 4 * NDG) {
                int d = g >> 8, b = g & 255;
                row_base = b * SEQ + 1 + d * (NOBJ + 1) + q * 16;
            } else {
                int b = g - NDG;
                row_base = b * SEQ + 1 + NDEMO * (NOBJ + 1) + q * 16;
            }
            int row = row_base + l15;
#pragma unroll
            for (int jj = 0; jj < 2; ++jj) {
                f32x4 v = acc[jj] + bv4[jj];
                __builtin_nontemporal_store(
                    v, reinterpret_cast<f32x4*>(out + (size_t)row * TOK + n0 + jj * 16 + l4 * 4));
            }
        }

    } else if (blk < OBJ_BLKS + ACT_BLKS) {
        // ================= action rows: 8 groups, 4 per 256-thread half ====
        int sub = tid >> 8;             // 0..1
        int t = tid & 255;
        int g4 = (blk - OBJ_BLKS) * 8 + sub * 4;
        float v[4];
        float bb = b_act[t];
#pragma unroll
        for (int r = 0; r < 4; ++r) v[r] = bb;
#pragma unroll
        for (int k = 0; k < 7; ++k) {
            float wv = W_act[k * TOK + t];
#pragma unroll
            for (int r = 0; r < 4; ++r)
                v[r] += demo_act[(size_t)(g4 + r) * 7 + k] * wv;
        }
#pragma unroll
        for (int r = 0; r < 4; ++r) {
            int g = g4 + r;
            int d = g >> 8, b = g & 255;
            out[(size_t)(b * SEQ + (d + 1) * (NOBJ + 1)) * TOK + t] = v[r];
        }

    } else {
        // ================= instr rows: one per 256-thread half, K=768 ======
        int sub = tid >> 8;
        int t = tid & 255;
        int row = (blk - OBJ_BLKS - ACT_BLKS) * 2 + sub;
        float* buf = &F[0][0];          // 2 x 768 f32 = 6 KB
        const float* src = instr + (size_t)row * 768;
#pragma unroll
        for (int i = 0; i < 3; ++i) buf[sub * 768 + i * 256 + t] = src[i * 256 + t];
        __syncthreads();
        float a0 = b_instr[t];
#pragma unroll 4
        for (int k = 0; k < 768; ++k)
            a0 += buf[sub * 768 + k] * W_instr[(size_t)k * TOK + t];
        out[(size_t)row * SEQ * TOK + t] = a0;
    }
}

extern "C" void kernel_launch(void* const* d_in, const int* in_sizes, int n_in,
                              void* d_out, int out_size, void* d_ws, size_t ws_size,
                              hipStream_t stream) {
    (void)in_sizes; (void)n_in; (void)out_size; (void)ws_size;
    const float* instr    = (const float*)d_in[0];
    const float* demo_obj = (const float*)d_in[1];
    const float* demo_act = (const float*)d_in[2];
    const float* cur      = (const float*)d_in[3];
    const float* W_instr  = (const float*)d_in[4];
    const float* b_instr  = (const float*)d_in[5];
    const float* W_act    = (const float*)d_in[6];
    const float* b_act    = (const float*)d_in[7];
    const float* W_obj    = (const float*)d_in[8];
    const float* b_obj    = (const float*)d_in[9];
    float* out = (float*)d_out;

    uint16_t* Wf = (uint16_t*)d_ws;   // 128 KB fragment-ordered bf16 weights

    wconv_frag_kernel<<<32, 256, 0, stream>>>(W_obj, Wf);
    fused_kernel<<<TOTAL_BLKS, 512, 0, stream>>>(
        demo_obj, cur, b_obj, (const __bf16*)d_ws,
        demo_act, W_act, b_act, instr, W_instr, b_instr, out);
}